// Round 11
// baseline (91.845 us; speedup 1.0000x reference)
//
#include <hip/hip_runtime.h>
#include <hip/hip_bf16.h>

// Problem constants (from reference)
#define BS    4
#define CH    64
#define HH    32
#define WW    88
#define NZ    60
#define BEV_Z 10
#define BEV_X 128
#define BEV_Y 128

static constexpr int HW        = HH * WW;        // 2816
static constexpr int ZX        = BEV_Z * BEV_X;  // 1280
static constexpr int PTS_PER_B = NZ * HW;        // 168960

static constexpr int T            = 16;              // hw columns per count tile
static constexpr int NT           = HW / T;          // 176 tiles per batch
static constexpr int CNT_BLOCKS   = BS * NT;         // 704
static constexpr int NXELEM       = BS * CH * HW;    // 720896
static constexpr int XCONV_BLOCKS = NXELEM / 4096;   // 176
static constexpr int CNT_WORDS    = ZX * T / 4;      // 5120 u32 words (20 KB tile)
static constexpr int TILE_BYTES   = ZX * T;          // 20480

static constexpr int BPTS   = NZ * T;                // 960 points per count block
static constexpr int FSLAB4 = BPTS * 3 / 4;          // 720 uint4 (11.5 KB)

static constexpr int NZG    = ZX / 16;               // 80 zx-groups of 16
static constexpr int QK     = HW / 4;                // 704 k per K-quarter
static constexpr int ITERS  = QK / 32;               // 22 MFMA iters per wave

typedef __attribute__((ext_vector_type(8))) short short8;   // bf16x8 MFMA frag
typedef __attribute__((ext_vector_type(4))) float floatx4;  // fp32x4 acc

__device__ inline unsigned short f2b(float v) {
    __hip_bfloat16 h = __float2bfloat16(v);
    return *reinterpret_cast<unsigned short*>(&h);
}

// u8 count (exact int <=60) -> bf16 bits: cvt to f32 (exact), take top 16
__device__ inline short cnt2bf(unsigned int w, int s) {
    float fv = (float)((w >> s) & 255u);   // v_cvt_f32_ubyte_n
    unsigned int u;
    __builtin_memcpy(&u, &fv, 4);
    return (short)(u >> 16);
}

// ---- K1: blocks 0..703 build u8 count tiles (tile-major, coalesced dump);
//          blocks 704..879 cast x fp32 -> bf16 ----
__global__ __launch_bounds__(256)
void build_kernel(const float* __restrict__ x, const int* __restrict__ f,
                  unsigned int* __restrict__ cnt8,
                  unsigned short* __restrict__ xbf) {
    __shared__ unsigned int cnt[CNT_WORDS];   // [zx][hw_l] u8-packed, 20 KB
    __shared__ uint4 fslab[FSLAB4];           // staged frustum slab, 11.5 KB
    int blk = blockIdx.x;
    if (blk < CNT_BLOCKS) {
        int b   = blk / NT;
        int t   = blk % NT;
        int hw0 = t * T;
        for (int i = threadIdx.x; i < CNT_WORDS; i += 256) cnt[i] = 0u;

        // stage f for this block's 960 points: fully coalesced 16B loads
        int p0 = b * PTS_PER_B + hw0;                    // multiple of 16
        const uint4* fb = (const uint4*)(f + (size_t)p0 * 3);
        constexpr int SEG4 = HW * 3 / 4;                 // uint4 stride per z (2112)
        for (int i = threadIdx.x; i < FSLAB4; i += 256) {
            int z = i / 12, w16 = i % 12;
            fslab[i] = fb[(size_t)z * SEG4 + w16];
        }
        __syncthreads();

        const unsigned int* fs = (const unsigned int*)fslab;
        #pragma unroll
        for (int r = 0; r < 4; ++r) {
            int j = r * 256 + threadIdx.x;               // point idx in block
            if (j < BPTS) {
                int xx = (int)fs[j * 3 + 0];
                int yy = (int)fs[j * 3 + 1];
                int zz = (int)fs[j * 3 + 2];
                bool kept = (xx >= 0) & (xx < BEV_X) & (yy >= 0) & (yy < BEV_Y) &
                            (zz >= 0) & (zz < BEV_Z);
                if (kept) {
                    int hw_l = j & 15;                   // j = z*16 + hw_l
                    int cell = (zz * BEV_X + xx) * T + hw_l;   // counts <= 60
                    atomicAdd(&cnt[cell >> 2], 1u << (8 * (cell & 3)));
                }
            }
        }
        __syncthreads();

        // contiguous 20 KB dump: cnt8[b][t][zx*16+hw_l] u8 == word-for-word LDS
        unsigned int* obase = cnt8 + (size_t)(b * NT + t) * CNT_WORDS;
        for (int i = threadIdx.x; i < CNT_WORDS; i += 256) obase[i] = cnt[i];
    } else {
        // cast x (b,ch,hw) fp32 -> bf16, same layout
        size_t base = (size_t)(blk - CNT_BLOCKS) * 4096;
        #pragma unroll
        for (int r = 0; r < 4; ++r) {
            size_t i = base + ((size_t)r * 256 + threadIdx.x) * 4;
            floatx4 v = *(const floatx4*)(x + i);
            ushort4 o;
            o.x = f2b(v.x); o.y = f2b(v.y); o.z = f2b(v.z); o.w = f2b(v.w);
            *(ushort4*)(xbf + i) = o;
        }
    }
}

// ---- K2: fused GEMM + in-block K-reduce. Block = (b, 16-zx group), 1024 thr.
// Wave w = (K-quarter q = w>>2, ch-tile c = w&3): one 16x16 output tile over
// K/4 = 704 (22 iters, 1 MFMA each). LDS-reduce the 4 K-quarters, store fp32.
// Fragment layouts verified R6-R10. 4-deep load rotation: ~6 VGPR/iter in
// flight, fits the 64-VGPR budget of __launch_bounds__(1024,8) = 2 blocks/CU.
__global__ __launch_bounds__(1024, 8)
void gemm_fused(const unsigned short* __restrict__ xbf,
                const unsigned char* __restrict__ cnt8,
                float* __restrict__ out) {
    __shared__ floatx4 red[3][4][64];     // 12 KB: partials of q=1..3
    int blk  = blockIdx.x;                // 0..319
    int b    = blk / NZG;
    int zx0  = (blk % NZG) * 16;
    int wid  = threadIdx.x >> 6;          // 0..15
    int c    = wid & 3;                   // ch-tile
    int q    = wid >> 2;                  // K-quarter
    int lane = threadIdx.x & 63;
    int m    = lane & 15;
    int quad = lane >> 4;
    int zx   = zx0 + m;

    const unsigned char* pb = cnt8 + (size_t)b * NT * TILE_BYTES
                            + (size_t)(q * (QK / T) + (quad >> 1)) * TILE_BYTES
                            + zx * T + (quad & 1) * 8;
    const unsigned short* pa = xbf + ((size_t)(b * CH) + c * 16 + m) * HW
                             + q * QK + quad * 8;

    uint2  wv[4];
    short8 av[4];
    #pragma unroll
    for (int i = 0; i < 4; ++i) {
        wv[i] = *(const uint2*)(pb + (size_t)(2 * i) * TILE_BYTES);
        av[i] = *(const short8*)(pa + i * 32);
    }

    floatx4 acc = {0.f, 0.f, 0.f, 0.f};
    #pragma unroll
    for (int i = 0; i < ITERS; ++i) {
        int s = i & 3;
        uint2  w = wv[s];
        short8 a = av[s];
        if (i + 4 < ITERS) {
            wv[s] = *(const uint2*)(pb + (size_t)(2 * (i + 4)) * TILE_BYTES);
            av[s] = *(const short8*)(pa + (i + 4) * 32);
        }
        short8 bf;
        bf[0] = cnt2bf(w.x,  0); bf[1] = cnt2bf(w.x,  8);
        bf[2] = cnt2bf(w.x, 16); bf[3] = cnt2bf(w.x, 24);
        bf[4] = cnt2bf(w.y,  0); bf[5] = cnt2bf(w.y,  8);
        bf[6] = cnt2bf(w.y, 16); bf[7] = cnt2bf(w.y, 24);
        acc = __builtin_amdgcn_mfma_f32_16x16x32_bf16(a, bf, acc, 0, 0, 0);
    }

    if (q) red[q - 1][c][lane] = acc;
    __syncthreads();
    if (q == 0) {
        floatx4 r0 = red[0][c][lane];
        floatx4 r1 = red[1][c][lane];
        floatx4 r2 = red[2][c][lane];
        acc += r0 + r1 + r2;
        float* ob = out + ((size_t)(b * CH + c * 16 + quad * 4)) * ZX + zx;
        #pragma unroll
        for (int r = 0; r < 4; ++r) ob[r * ZX] = acc[r];
    }
}

extern "C" void kernel_launch(void* const* d_in, const int* in_sizes, int n_in,
                              void* d_out, int out_size, void* d_ws, size_t ws_size,
                              hipStream_t stream) {
    const float* x = (const float*)d_in[0];
    const int*   f = (const int*)d_in[1];
    float*       out = (float*)d_out;

    char* ws = (char*)d_ws;
    size_t off = 0;
    auto carve = [&](size_t bytes) {
        char* p = ws + off;
        off += (bytes + 255) & ~(size_t)255;
        return p;
    };
    unsigned int*   cnt8 = (unsigned int*)  carve((size_t)BS * NT * TILE_BYTES); // 14.4 MB
    unsigned short* xbf  = (unsigned short*)carve((size_t)NXELEM * 2);           // 1.44 MB
    // both fully written by K1 before K2 reads them -> no memsets needed

    build_kernel<<<CNT_BLOCKS + XCONV_BLOCKS, 256, 0, stream>>>(x, f, cnt8, xbf);
    gemm_fused  <<<BS * NZG, 1024, 0, stream>>>(xbf, (const unsigned char*)cnt8, out);
}

// Round 12
// 89.402 us; speedup vs baseline: 1.0273x; 1.0273x over previous
//
#include <hip/hip_runtime.h>
#include <hip/hip_bf16.h>

// Problem constants (from reference)
#define BS    4
#define CH    64
#define HH    32
#define WW    88
#define NZ    60
#define BEV_Z 10
#define BEV_X 128
#define BEV_Y 128

static constexpr int HW        = HH * WW;        // 2816
static constexpr int ZX        = BEV_Z * BEV_X;  // 1280
static constexpr int PTS_PER_B = NZ * HW;        // 168960

static constexpr int T            = 16;              // hw columns per count tile
static constexpr int NT           = HW / T;          // 176 tiles per batch
static constexpr int CNT_BLOCKS   = BS * NT;         // 704
static constexpr int NXELEM       = BS * CH * HW;    // 720896
static constexpr int XCONV_BLOCKS = NXELEM / 4096;   // 176
static constexpr int CNT_WORDS    = ZX * T / 4;      // 5120 u32 words (20 KB tile)
static constexpr int TILE_BYTES   = ZX * T;          // 20480
static constexpr int ZGROUPS      = ZX / 64;         // 20

static constexpr int KS     = 11;                    // K-split chunks (R9 best)
static constexpr int KCH    = HW / KS;               // 256 hw per chunk, 8 iters
static constexpr int OUTSZ  = BS * CH * ZX;          // 327680

static constexpr int BPTS   = NZ * T;                // 960 points per count block
static constexpr int FSLAB4 = BPTS * 3 / 4;          // 720 uint4 (11.5 KB)

typedef __attribute__((ext_vector_type(8))) short short8;   // bf16x8 MFMA frag
typedef __attribute__((ext_vector_type(4))) float floatx4;  // fp32x4 acc

__device__ inline unsigned short f2b(float v) {
    __hip_bfloat16 h = __float2bfloat16(v);
    return *reinterpret_cast<unsigned short*>(&h);
}

// u8 count (exact int <=60) -> bf16 bits: cvt to f32 (exact), take top 16
__device__ inline short cnt2bf(unsigned int w, int s) {
    float fv = (float)((w >> s) & 255u);   // v_cvt_f32_ubyte_n
    unsigned int u;
    __builtin_memcpy(&u, &fv, 4);
    return (short)(u >> 16);
}

__device__ inline float bfbits2f(unsigned int bits) {   // bits already in [31:16]
    float fv;
    __builtin_memcpy(&fv, &bits, 4);
    return fv;
}

// ---- K1: blocks 0..703 build u8 count tiles (tile-major, coalesced dump);
//          blocks 704..879 cast x fp32 -> bf16 ----
__global__ __launch_bounds__(256)
void build_kernel(const float* __restrict__ x, const int* __restrict__ f,
                  unsigned int* __restrict__ cnt8,
                  unsigned short* __restrict__ xbf) {
    __shared__ unsigned int cnt[CNT_WORDS];   // [zx][hw_l] u8-packed, 20 KB
    __shared__ uint4 fslab[FSLAB4];           // staged frustum slab, 11.5 KB
    int blk = blockIdx.x;
    if (blk < CNT_BLOCKS) {
        int b   = blk / NT;
        int t   = blk % NT;
        int hw0 = t * T;
        for (int i = threadIdx.x; i < CNT_WORDS; i += 256) cnt[i] = 0u;

        // stage f for this block's 960 points: fully coalesced 16B loads
        int p0 = b * PTS_PER_B + hw0;                    // multiple of 16
        const uint4* fb = (const uint4*)(f + (size_t)p0 * 3);
        constexpr int SEG4 = HW * 3 / 4;                 // uint4 stride per z (2112)
        for (int i = threadIdx.x; i < FSLAB4; i += 256) {
            int z = i / 12, w16 = i % 12;
            fslab[i] = fb[(size_t)z * SEG4 + w16];
        }
        __syncthreads();

        const unsigned int* fs = (const unsigned int*)fslab;
        #pragma unroll
        for (int r = 0; r < 4; ++r) {
            int j = r * 256 + threadIdx.x;               // point idx in block
            if (j < BPTS) {
                int xx = (int)fs[j * 3 + 0];
                int yy = (int)fs[j * 3 + 1];
                int zz = (int)fs[j * 3 + 2];
                bool kept = ((unsigned)xx < BEV_X) & ((unsigned)yy < BEV_Y) &
                            ((unsigned)zz < BEV_Z);
                if (kept) {
                    int hw_l = j & 15;                   // j = z*16 + hw_l
                    int cell = (zz * BEV_X + xx) * T + hw_l;   // counts <= 60
                    atomicAdd(&cnt[cell >> 2], 1u << (8 * (cell & 3)));
                }
            }
        }
        __syncthreads();

        // contiguous 20 KB dump: cnt8[b][t][zx*16+hw_l] u8 == word-for-word LDS
        unsigned int* obase = cnt8 + (size_t)(b * NT + t) * CNT_WORDS;
        for (int i = threadIdx.x; i < CNT_WORDS; i += 256) obase[i] = cnt[i];
    } else {
        // cast x (b,ch,hw) fp32 -> bf16, same layout
        size_t base = (size_t)(blk - CNT_BLOCKS) * 4096;
        #pragma unroll
        for (int r = 0; r < 4; ++r) {
            size_t i = base + ((size_t)r * 256 + threadIdx.x) * 4;
            floatx4 v = *(const floatx4*)(x + i);
            ushort4 o;
            o.x = f2b(v.x); o.y = f2b(v.y); o.z = f2b(v.z); o.w = f2b(v.w);
            *(ushort4*)(xbf + i) = o;
        }
    }
}

// ---- K2: K-split GEMM (R9 shape). Block = (b, 64-zx group, K-chunk of 256).
// 4 waves; wave = 16-zx tile; 4 ch-tile accumulators (B loaded ONCE per iter,
// amortized over 4 MFMA). Explicit 4-deep rotated preload keeps ~20 loads in
// flight; __launch_bounds__(256,4) lifts the VGPR budget to ~128 so the
// compiler cannot re-serialize them (R7 showed VGPR=40 => latency-bound).
__global__ __launch_bounds__(256, 4)
void gemm_kernel(const unsigned short* __restrict__ xbf,
                 const unsigned char* __restrict__ cnt8,
                 unsigned short* __restrict__ P) {
    int blk  = blockIdx.x;                 // 0..879
    int kc   = blk % KS;
    int r2   = blk / KS;
    int b    = r2 / ZGROUPS;
    int zg   = r2 % ZGROUPS;
    int wave = threadIdx.x >> 6;
    int lane = threadIdx.x & 63;
    int m    = lane & 15;
    int quad = lane >> 4;
    int zx   = zg * 64 + wave * 16 + m;
    int k0   = kc * KCH;

    const unsigned char* pb = cnt8 + (size_t)b * NT * TILE_BYTES
                            + (size_t)(k0 / T + (quad >> 1)) * TILE_BYTES
                            + zx * T + (quad & 1) * 8;
    const unsigned short* pa = xbf + ((size_t)(b * CH) + m) * HW + k0 + quad * 8;

    // 4-deep rotating preload: 4 uint2 + 16 short8 = 72 payload VGPRs
    uint2  wv[4];
    short8 av[4][4];
    #pragma unroll
    for (int i = 0; i < 4; ++i) {
        wv[i] = *(const uint2*)(pb + (size_t)(2 * i) * TILE_BYTES);
        #pragma unroll
        for (int c = 0; c < 4; ++c)
            av[i][c] = *(const short8*)(pa + c * 16 * HW + i * 32);
    }

    floatx4 acc0 = {0.f,0.f,0.f,0.f}, acc1 = {0.f,0.f,0.f,0.f};
    floatx4 acc2 = {0.f,0.f,0.f,0.f}, acc3 = {0.f,0.f,0.f,0.f};

    #pragma unroll
    for (int i = 0; i < 8; ++i) {          // KCH/32 = 8 iterations
        int s = i & 3;
        uint2  w  = wv[s];
        short8 a0 = av[s][0], a1 = av[s][1], a2 = av[s][2], a3 = av[s][3];
        if (i < 4) {                       // refill slot for iter i+4
            wv[s] = *(const uint2*)(pb + (size_t)(2 * (i + 4)) * TILE_BYTES);
            #pragma unroll
            for (int c = 0; c < 4; ++c)
                av[s][c] = *(const short8*)(pa + c * 16 * HW + (i + 4) * 32);
        }
        short8 bf;
        bf[0] = cnt2bf(w.x,  0); bf[1] = cnt2bf(w.x,  8);
        bf[2] = cnt2bf(w.x, 16); bf[3] = cnt2bf(w.x, 24);
        bf[4] = cnt2bf(w.y,  0); bf[5] = cnt2bf(w.y,  8);
        bf[6] = cnt2bf(w.y, 16); bf[7] = cnt2bf(w.y, 24);

        acc0 = __builtin_amdgcn_mfma_f32_16x16x32_bf16(a0, bf, acc0, 0, 0, 0);
        acc1 = __builtin_amdgcn_mfma_f32_16x16x32_bf16(a1, bf, acc1, 0, 0, 0);
        acc2 = __builtin_amdgcn_mfma_f32_16x16x32_bf16(a2, bf, acc2, 0, 0, 0);
        acc3 = __builtin_amdgcn_mfma_f32_16x16x32_bf16(a3, bf, acc3, 0, 0, 0);
    }

    unsigned short* op = P + ((size_t)(kc * BS + b) * CH) * ZX + zx;
    #pragma unroll
    for (int r = 0; r < 4; ++r) {
        int ch = quad * 4 + r;
        op[(0 * 16 + ch) * ZX] = f2b(acc0[r]);
        op[(1 * 16 + ch) * ZX] = f2b(acc1[r]);
        op[(2 * 16 + ch) * ZX] = f2b(acc2[r]);
        op[(3 * 16 + ch) * ZX] = f2b(acc3[r]);
    }
}

// ---- K3: out = sum of 11 bf16 K-chunk partials; 2 outputs per thread ----
__global__ __launch_bounds__(256)
void reduce_kernel(const unsigned int* __restrict__ P, float* __restrict__ out) {
    int idx = blockIdx.x * 256 + threadIdx.x;    // 0..OUTSZ/2-1, pair index
    float s_lo = 0.f, s_hi = 0.f;
    #pragma unroll
    for (int kc = 0; kc < KS; ++kc) {
        unsigned int u = P[(size_t)kc * (OUTSZ / 2) + idx];
        s_lo += bfbits2f(u << 16);
        s_hi += bfbits2f(u & 0xFFFF0000u);
    }
    *(float2*)(out + (size_t)idx * 2) = make_float2(s_lo, s_hi);
}

extern "C" void kernel_launch(void* const* d_in, const int* in_sizes, int n_in,
                              void* d_out, int out_size, void* d_ws, size_t ws_size,
                              hipStream_t stream) {
    const float* x = (const float*)d_in[0];
    const int*   f = (const int*)d_in[1];
    float*       out = (float*)d_out;

    char* ws = (char*)d_ws;
    size_t off = 0;
    auto carve = [&](size_t bytes) {
        char* p = ws + off;
        off += (bytes + 255) & ~(size_t)255;
        return p;
    };
    unsigned int*   cnt8 = (unsigned int*)  carve((size_t)BS * NT * TILE_BYTES); // 14.4 MB
    unsigned short* xbf  = (unsigned short*)carve((size_t)NXELEM * 2);           // 1.44 MB
    unsigned short* P    = (unsigned short*)carve((size_t)KS * OUTSZ * 2);       // 7.2 MB
    // all fully written before being read -> no memsets needed

    build_kernel <<<CNT_BLOCKS + XCONV_BLOCKS, 256, 0, stream>>>(x, f, cnt8, xbf);
    gemm_kernel  <<<BS * ZGROUPS * KS, 256, 0, stream>>>(xbf, (const unsigned char*)cnt8, P);
    reduce_kernel<<<OUTSZ / 2 / 256, 256, 0, stream>>>((const unsigned int*)P, out);
}